// Round 5
// baseline (290.577 us; speedup 1.0000x reference)
//
#include <hip/hip_runtime.h>
#include <hip/hip_bf16.h>
#include <stdint.h>

#define B_ 2
#define S_ 2048
#define D_ 2048
#define H_ 32
#define KV_ 8
#define HD_ 64
#define NQKV 3072   // D + 2*KV*HD

typedef __bf16 bf16_t;
typedef __bf16 bf16x8 __attribute__((ext_vector_type(8)));
typedef __bf16 bf16x4 __attribute__((ext_vector_type(4)));
typedef float  f32x4  __attribute__((ext_vector_type(4)));
typedef float  f32x16 __attribute__((ext_vector_type(16)));
typedef unsigned int u32;
typedef u32 u32x4 __attribute__((ext_vector_type(4)));

typedef const __attribute__((address_space(1))) uint32_t* gp1_t;
typedef __attribute__((address_space(3))) uint32_t* lp3_t;

// async global->LDS, 16B per lane. LDS dest is wave-uniform base + lane*16.
__device__ inline void gload_lds16(const void* g, void* l) {
  __builtin_amdgcn_global_load_lds((gp1_t)(uintptr_t)g, (lp3_t)(uint32_t)(uintptr_t)l,
                                   16, 0, 0);
}

__device__ inline u32 pkbf(float a, float b) {
  union { bf16_t h[2]; u32 u; } v;
  v.h[0] = (bf16_t)a; v.h[1] = (bf16_t)b;
  return v.u;
}

// v_permlane32_swap_b32: a = [a_lo, b_lo], b = [a_hi, b_hi]
__device__ inline void pl32swap(u32 &a, u32 &b) {
  asm("v_permlane32_swap_b32 %0, %1" : "+v"(a), "+v"(b));
}

// ---------------- converts ----------------
__global__ void cvt_f32_bf16(const float* __restrict__ in, bf16_t* __restrict__ out, int n4) {
  int i = blockIdx.x * blockDim.x + threadIdx.x;
  if (i < n4) {
    float4 v = ((const float4*)in)[i];
    bf16x4 o;
    o[0] = (bf16_t)v.x; o[1] = (bf16_t)v.y; o[2] = (bf16_t)v.z; o[3] = (bf16_t)v.w;
    ((bf16x4*)out)[i] = o;
  }
}

// transpose + cast: out[row_off + c][r] = in[r][c]
__global__ void transpose_cvt(const float* __restrict__ in, bf16_t* __restrict__ out,
                              int C, int row_off) {
  __shared__ float t[32][33];
  int tx = threadIdx.x, ty = threadIdx.y;       // (32,8)
  int c0 = blockIdx.x * 32, r0 = blockIdx.y * 32;
#pragma unroll
  for (int j = 0; j < 4; ++j)
    t[ty + j*8][tx] = in[(int64_t)(r0 + ty + j*8) * C + c0 + tx];
  __syncthreads();
#pragma unroll
  for (int j = 0; j < 4; ++j)
    out[(int64_t)(row_off + c0 + ty + j*8) * 2048 + r0 + tx] = (bf16_t)t[tx][ty + j*8];
}

// ---------------- plain GEMM: C = A @ B, Bt = B^T (N x K) ----------------
template <typename OutT>
__global__ __launch_bounds__(256) void gemm_bt(const bf16_t* __restrict__ A,
                                               const bf16_t* __restrict__ Bt,
                                               OutT* __restrict__ C,
                                               int M, int N, int K) {
  __shared__ bf16_t As[128 * 32];
  __shared__ bf16_t Bs[128 * 32];
  const int tid = threadIdx.x;
  const int wid = tid >> 6, lane = tid & 63;
  const int l15 = lane & 15, l4 = lane >> 4;
  const int bm = blockIdx.y * 128, bn = blockIdx.x * 128;
  const int wm = (wid >> 1) * 64, wn = (wid & 1) * 64;

  f32x4 acc[4][4] = {};

  const int arow0 = tid >> 2;
  const int kslot = (tid & 3) * 8;
  const bf16_t* Ag0 = A  + (int64_t)(bm + arow0)      * K + kslot;
  const bf16_t* Ag1 = A  + (int64_t)(bm + arow0 + 64) * K + kslot;
  const bf16_t* Bg0 = Bt + (int64_t)(bn + arow0)      * K + kslot;
  const bf16_t* Bg1 = Bt + (int64_t)(bn + arow0 + 64) * K + kslot;
  char* AsB = (char*)As + wid * 1024;
  char* BsB = (char*)Bs + wid * 1024;

  for (int k0 = 0; k0 < K; k0 += 32) {
    gload_lds16(Ag0 + k0, AsB);
    gload_lds16(Ag1 + k0, AsB + 4096);
    gload_lds16(Bg0 + k0, BsB);
    gload_lds16(Bg1 + k0, BsB + 4096);
    asm volatile("s_waitcnt vmcnt(0)" ::: "memory");
    __syncthreads();

    bf16x8 af[4], bfr[4];
#pragma unroll
    for (int m = 0; m < 4; ++m)
      af[m] = *(const bf16x8*)(As + (wm + m*16 + l15) * 32 + l4 * 8);
#pragma unroll
    for (int n = 0; n < 4; ++n)
      bfr[n] = *(const bf16x8*)(Bs + (wn + n*16 + l15) * 32 + l4 * 8);
#pragma unroll
    for (int m = 0; m < 4; ++m)
#pragma unroll
      for (int n = 0; n < 4; ++n)
        acc[m][n] = __builtin_amdgcn_mfma_f32_16x16x32_bf16(af[m], bfr[n], acc[m][n], 0, 0, 0);
    __syncthreads();
  }

#pragma unroll
  for (int m = 0; m < 4; ++m) {
    const int row = bm + wm + m*16 + l4*4;
#pragma unroll
    for (int n = 0; n < 4; ++n) {
      const int col = bn + wn + n*16 + l15;
#pragma unroll
      for (int r = 0; r < 4; ++r)
        C[(int64_t)(row + r) * N + col] = (OutT)acc[m][n][r];
    }
  }
}

// ---------------- QKV GEMM with fused RoPE / scatter / V-transpose ----------------
// A: (B*S) x 2048 bf16 (x). Bt: 3072 x 2048 bf16 ([Wq|Wk|Wv]^T).
// Epilogue: cols [0,2048) -> RoPE*QSCALE -> Q[b][h][s][d]
//           cols [2048,2560) -> RoPE -> Kr[b][kvh][s][d]
//           cols [2560,3072) -> Vt[b][cc][s]  (transposed)
// A wave's 64-col span lies in one head; RoPE partner d^32 is acc[m][n^2][r] (same lane).
#define QSCALE 0.18033688011112042f
__global__ __launch_bounds__(256) void gemm_qkv(const bf16_t* __restrict__ A,
                                                const bf16_t* __restrict__ Bt,
                                                const float* __restrict__ cosb,
                                                const float* __restrict__ sinb,
                                                bf16_t* __restrict__ Q,
                                                bf16_t* __restrict__ Kr,
                                                bf16_t* __restrict__ Vt) {
  constexpr int K = 2048;
  __shared__ bf16_t As[128 * 32];
  __shared__ bf16_t Bs[128 * 32];
  const int tid = threadIdx.x;
  const int wid = tid >> 6, lane = tid & 63;
  const int l15 = lane & 15, l4 = lane >> 4;
  const int bm = blockIdx.y * 128, bn = blockIdx.x * 128;
  const int wm = (wid >> 1) * 64, wn = (wid & 1) * 64;

  f32x4 acc[4][4] = {};

  const int arow0 = tid >> 2;
  const int kslot = (tid & 3) * 8;
  const bf16_t* Ag0 = A  + (int64_t)(bm + arow0)      * K + kslot;
  const bf16_t* Ag1 = A  + (int64_t)(bm + arow0 + 64) * K + kslot;
  const bf16_t* Bg0 = Bt + (int64_t)(bn + arow0)      * K + kslot;
  const bf16_t* Bg1 = Bt + (int64_t)(bn + arow0 + 64) * K + kslot;
  char* AsB = (char*)As + wid * 1024;
  char* BsB = (char*)Bs + wid * 1024;

  for (int k0 = 0; k0 < K; k0 += 32) {
    gload_lds16(Ag0 + k0, AsB);
    gload_lds16(Ag1 + k0, AsB + 4096);
    gload_lds16(Bg0 + k0, BsB);
    gload_lds16(Bg1 + k0, BsB + 4096);
    asm volatile("s_waitcnt vmcnt(0)" ::: "memory");
    __syncthreads();

    bf16x8 af[4], bfr[4];
#pragma unroll
    for (int m = 0; m < 4; ++m)
      af[m] = *(const bf16x8*)(As + (wm + m*16 + l15) * 32 + l4 * 8);
#pragma unroll
    for (int n = 0; n < 4; ++n)
      bfr[n] = *(const bf16x8*)(Bs + (wn + n*16 + l15) * 32 + l4 * 8);
#pragma unroll
    for (int m = 0; m < 4; ++m)
#pragma unroll
      for (int n = 0; n < 4; ++n)
        acc[m][n] = __builtin_amdgcn_mfma_f32_16x16x32_bf16(af[m], bfr[n], acc[m][n], 0, 0, 0);
    __syncthreads();
  }

  const int colbase = bn + wn;            // multiple of 64 -> wave-uniform region/head
  if (colbase < 2048) {                   // -------- Q region (RoPE + scale) --------
    const int h = colbase >> 6;
#pragma unroll
    for (int m = 0; m < 4; ++m) {
#pragma unroll
      for (int r = 0; r < 4; ++r) {
        const int srow = bm + wm + m*16 + l4*4 + r;
        const int b = srow >> 11, s = srow & 2047;
        const float* cs = cosb + s * HD_;
        const float* sn = sinb + s * HD_;
        bf16_t* qp = Q + ((int64_t)(b * H_ + h) * S_ + s) * HD_;
#pragma unroll
        for (int n = 0; n < 4; ++n) {
          const int d = n*16 + l15;
          const float sgn = (n & 2) ? 1.f : -1.f;
          float o = (acc[m][n][r] * cs[d] + sgn * acc[m][n^2][r] * sn[d]) * QSCALE;
          qp[d] = (bf16_t)o;
        }
      }
    }
  } else if (colbase < 2560) {            // -------- K region (RoPE) --------
    const int kvh = (colbase - 2048) >> 6;
#pragma unroll
    for (int m = 0; m < 4; ++m) {
#pragma unroll
      for (int r = 0; r < 4; ++r) {
        const int srow = bm + wm + m*16 + l4*4 + r;
        const int b = srow >> 11, s = srow & 2047;
        const float* cs = cosb + s * HD_;
        const float* sn = sinb + s * HD_;
        bf16_t* kp = Kr + ((int64_t)(b * KV_ + kvh) * S_ + s) * HD_;
#pragma unroll
        for (int n = 0; n < 4; ++n) {
          const int d = n*16 + l15;
          const float sgn = (n & 2) ? 1.f : -1.f;
          float o = acc[m][n][r] * cs[d] + sgn * acc[m][n^2][r] * sn[d];
          kp[d] = (bf16_t)o;
        }
      }
    }
  } else {                                // -------- V region (transpose) --------
#pragma unroll
    for (int m = 0; m < 4; ++m) {
#pragma unroll
      for (int r = 0; r < 4; ++r) {
        const int srow = bm + wm + m*16 + l4*4 + r;
        const int b = srow >> 11, s = srow & 2047;
#pragma unroll
        for (int n = 0; n < 4; ++n) {
          const int cc = colbase - 2560 + n*16 + l15;   // 0..511
          Vt[(int64_t)(b * 512 + cc) * S_ + s] = (bf16_t)acc[m][n][r];
        }
      }
    }
  }
}

// ---------------- flash attention, 2-wave blocks, paired kv-tiles ----------------
#define SHIFT_ 8.0f
__global__ __launch_bounds__(128) void attn3(const bf16_t* __restrict__ Q,
                                             const bf16_t* __restrict__ Kr,
                                             const bf16_t* __restrict__ Vt,
                                             bf16_t* __restrict__ AO) {
  const int hb = blockIdx.x;
  const int h = hb & 31, b = hb >> 5;
  const int qc = 31 - blockIdx.y;         // LPT: longest blocks first
  const int tid = threadIdx.x;
  const int w = tid >> 6, lane = tid & 63;
  const int l31 = lane & 31, hi = lane >> 5;
  const int kvh = h >> 2;                 // NREP = 4
  const int q0w = qc * 64 + w * 32;

  const bf16_t* Qb = Q  + ((int64_t)(b * H_ + h) * S_ + q0w) * HD_;
  const bf16_t* Kb = Kr + (int64_t)(b * KV_ + kvh) * S_ * HD_;
  const bf16_t* Vb = Vt + (int64_t)(b * KV_ + kvh) * HD_ * S_;

  bf16x8 qf[4];
#pragma unroll
  for (int ds = 0; ds < 4; ++ds)
    qf[ds] = *(const bf16x8*)(Qb + l31 * HD_ + ds * 16 + hi * 8);

  f32x16 accO0 = {}, accO1 = {};          // O^T rows d 0-31 / 32-63, col q = l31
  float lhalf = 0.f;                      // per-half-lane partial denominator
  const int ND = q0w >> 5;

  auto qk = [&](int kv0) -> f32x16 {
    f32x16 s = {};
    __builtin_amdgcn_s_setprio(1);
#pragma unroll
    for (int ds = 0; ds < 4; ++ds) {
      bf16x8 kf = *(const bf16x8*)(Kb + (int64_t)(kv0 + l31) * HD_ + ds * 16 + hi * 8);
      s = __builtin_amdgcn_mfma_f32_32x32x16_bf16(kf, qf[ds], s, 0, 0, 0);
    }
    __builtin_amdgcn_s_setprio(0);
    return s;
  };

  auto softmax_pf = [&](const f32x16 &sacc, bool maskdiag, bf16x8 &pf0, bf16x8 &pf1) {
    float p[16];
#pragma unroll
    for (int r = 0; r < 16; ++r) {
      float sc = sacc[r];
      if (maskdiag) {
        int kvpos = (r & 3) + 8 * (r >> 2) + 4 * hi;
        if (kvpos > l31) sc = -1e30f;
      }
      p[r] = __builtin_amdgcn_exp2f(sc - SHIFT_);
    }
    float t0 = (p[0] + p[1]) + (p[2] + p[3]);
    float t1 = (p[4] + p[5]) + (p[6] + p[7]);
    float t2 = (p[8] + p[9]) + (p[10] + p[11]);
    float t3 = (p[12] + p[13]) + (p[14] + p[15]);
    lhalf += (t0 + t1) + (t2 + t3);
    u32 pk[8];
#pragma unroll
    for (int i = 0; i < 8; ++i) pk[i] = pkbf(p[2*i], p[2*i+1]);
    u32 a0 = pk[0], b0 = pk[2]; pl32swap(a0, b0);
    u32 a1 = pk[1], b1 = pk[3]; pl32swap(a1, b1);
    u32 a2 = pk[4], b2 = pk[6]; pl32swap(a2, b2);
    u32 a3 = pk[5], b3 = pk[7]; pl32swap(a3, b3);
    pf0 = __builtin_bit_cast(bf16x8, (u32x4){a0, a1, b0, b1});
    pf1 = __builtin_bit_cast(bf16x8, (u32x4){a2, a3, b2, b3});
  };

  auto pv = [&](int kv0, bf16x8 pf0, bf16x8 pf1) {
    bf16x8 v00 = *(const bf16x8*)(Vb + (int64_t)l31 * S_ + kv0 + hi * 8);
    bf16x8 v01 = *(const bf16x8*)(Vb + (int64_t)l31 * S_ + kv0 + 16 + hi * 8);
    bf16x8 v10 = *(const bf16x8*)(Vb + (int64_t)(32 + l31) * S_ + kv0 + hi * 8);
    bf16x8 v11 = *(const bf16x8*)(Vb + (int64_t)(32 + l31) * S_ + kv0 + 16 + hi * 8);
    __builtin_amdgcn_s_setprio(1);
    accO0 = __builtin_amdgcn_mfma_f32_32x32x16_bf16(v00, pf0, accO0, 0, 0, 0);
    accO1 = __builtin_amdgcn_mfma_f32_32x32x16_bf16(v10, pf0, accO1, 0, 0, 0);
    accO0 = __builtin_amdgcn_mfma_f32_32x32x16_bf16(v01, pf1, accO0, 0, 0, 0);
    accO1 = __builtin_amdgcn_mfma_f32_32x32x16_bf16(v11, pf1, accO1, 0, 0, 0);
    __builtin_amdgcn_s_setprio(0);
  };

  int t = 0;
  for (; t + 2 <= ND; t += 2) {           // paired tiles: two independent chains
    f32x16 sA = qk(t * 32);
    f32x16 sB = qk(t * 32 + 32);
    bf16x8 pA0, pA1, pB0, pB1;
    softmax_pf(sA, false, pA0, pA1);
    softmax_pf(sB, false, pB0, pB1);
    pv(t * 32, pA0, pA1);
    pv(t * 32 + 32, pB0, pB1);
  }
  if (t < ND) {                           // leftover full tile
    f32x16 sA = qk(t * 32);
    bf16x8 pA0, pA1;
    softmax_pf(sA, false, pA0, pA1);
    pv(t * 32, pA0, pA1);
  }
  {                                       // diagonal tile
    f32x16 sA = qk(ND * 32);
    bf16x8 pA0, pA1;
    softmax_pf(sA, true, pA0, pA1);
    pv(ND * 32, pA0, pA1);
  }

  float lrun = lhalf + __shfl_xor(lhalf, 32);

  const float rl = 1.f / lrun;
  const int64_t row = (int64_t)(b * S_ + q0w + l31);
#pragma unroll
  for (int dt = 0; dt < 2; ++dt) {
#pragma unroll
    for (int g = 0; g < 4; ++g) {
      bf16x4 ov;
#pragma unroll
      for (int j = 0; j < 4; ++j) {
        float val = (dt ? accO1[4*g + j] : accO0[4*g + j]) * rl;
        ov[j] = (bf16_t)val;
      }
      const int d0 = dt * 32 + g * 8 + hi * 4;
      *(bf16x4*)(AO + row * D_ + h * HD_ + d0) = ov;
    }
  }
}

// ---------------- launcher ----------------
extern "C" void kernel_launch(void* const* d_in, const int* in_sizes, int n_in,
                              void* d_out, int out_size, void* d_ws, size_t ws_size,
                              hipStream_t stream) {
  const float* x    = (const float*)d_in[0];
  const float* cosb = (const float*)d_in[1];
  const float* sinb = (const float*)d_in[2];
  const float* Wq   = (const float*)d_in[3];
  const float* Wk   = (const float*)d_in[4];
  const float* Wv   = (const float*)d_in[5];
  const float* Wo   = (const float*)d_in[6];
  float* out = (float*)d_out;

  bf16_t* ws = (bf16_t*)d_ws;
  size_t o = 0;
  bf16_t* xb    = ws + o; o += (size_t)4096 * 2048;
  bf16_t* Wqkvt = ws + o; o += (size_t)3072 * 2048;
  bf16_t* Wot   = ws + o; o += (size_t)2048 * 2048;
  bf16_t* Qr    = ws + o; o += (size_t)B_ * H_ * S_ * HD_;
  bf16_t* Krb   = ws + o; o += (size_t)B_ * KV_ * S_ * HD_;
  bf16_t* Vtb   = ws + o; o += (size_t)B_ * KV_ * S_ * HD_;
  bf16_t* AO    = ws + o; o += (size_t)4096 * 2048;

  cvt_f32_bf16<<<(8388608/4 + 255)/256, 256, 0, stream>>>(x, xb, 8388608/4);
  transpose_cvt<<<dim3(2048/32, 2048/32), dim3(32, 8), 0, stream>>>(Wq, Wqkvt, 2048, 0);
  transpose_cvt<<<dim3(512/32, 2048/32),  dim3(32, 8), 0, stream>>>(Wk, Wqkvt, 512, 2048);
  transpose_cvt<<<dim3(512/32, 2048/32),  dim3(32, 8), 0, stream>>>(Wv, Wqkvt, 512, 2560);
  transpose_cvt<<<dim3(2048/32, 2048/32), dim3(32, 8), 0, stream>>>(Wo, Wot, 2048, 0);
  // fused QKV projection + RoPE + scatter + V-transpose
  gemm_qkv<<<dim3(3072/128, 4096/128), 256, 0, stream>>>(xb, Wqkvt, cosb, sinb, Qr, Krb, Vtb);
  // causal GQA attention (2-wave blocks)
  attn3<<<dim3(64, 32), 128, 0, stream>>>(Qr, Krb, Vtb, AO);
  // output projection -> f32
  gemm_bt<float><<<dim3(2048/128, 4096/128), 256, 0, stream>>>(AO, Wot, out, 4096, 2048, 2048);
}